// Round 11
// baseline (293.840 us; speedup 1.0000x reference)
//
#include <hip/hip_runtime.h>
#include <math.h>

#define N_NODES 4096
#define IN_DIM  1433
#define HID     64
#define OUT_DIM 7
#define FPAD    8       // padded feature stride for vectorized gathers
#define CAP     128     // max neighbors per node (avg 32, sigma 5.6; 128 >15 sigma)
#define BR      64      // rows per gemm tile block
#define KT      32      // k-tile
#define NBLK    64      // blocks in fused propagation kernel (co-resident)

static constexpr float LAMBDA = (float)(1.0 / 0.9 - 1.0);   // 0.11111111
static constexpr float SCADA  = 3.7f;

// clang ext-vector: maps onto a VGPR quad -> legal direct "v" asm operand
// (HIP float4 is a struct => "indirect register input" compile error, R10)
typedef float f32x4 __attribute__((ext_vector_type(4)));

// ---------------------------------------------------------------------------
// Kernel 1 (heterogeneous fused front), gemm-first block order (R8, passed):
//   blocks [0, NGEMM)            : gemm1 split-K tiles, P[ks] = X_chunk @ w1
//   blocks [NGEMM, NGEMM+N_NODES): adjacency extraction, one row per block
// Gemm block 0 also zero-inits the barrier counter for rung_fused.
// ---------------------------------------------------------------------------
__global__ __launch_bounds__(256) void front(const float* __restrict__ A,
    const float* __restrict__ X, const float* __restrict__ w1,
    int* __restrict__ nbr, int* __restrict__ cnt, float* __restrict__ deg,
    float* __restrict__ rsd, float* __restrict__ P,
    unsigned* __restrict__ bar, int ksplit) {
  __shared__ __align__(16) float lds[KT * (BR + 4) + KT * HID];
  const int b = blockIdx.x;
  const int t = threadIdx.x;
  const int ngemm = (N_NODES / BR) * ksplit;

  if (b >= ngemm) {
    // ---- adjacency path (one row per block) ----
    const int i = b - ngemm;
    int* cp = (int*)lds;
    if (t == 0) *cp = 0;
    __syncthreads();
    const float4* row = (const float4*)(A + (size_t)i * N_NODES);
    for (int q = t; q < N_NODES / 4; q += 256) {
      float4 v = row[q];
      int j0 = q * 4;
      if (v.x != 0.0f) { int s = atomicAdd(cp, 1); if (s < CAP) nbr[(size_t)i * CAP + s] = j0; }
      if (v.y != 0.0f) { int s = atomicAdd(cp, 1); if (s < CAP) nbr[(size_t)i * CAP + s] = j0 + 1; }
      if (v.z != 0.0f) { int s = atomicAdd(cp, 1); if (s < CAP) nbr[(size_t)i * CAP + s] = j0 + 2; }
      if (v.w != 0.0f) { int s = atomicAdd(cp, 1); if (s < CAP) nbr[(size_t)i * CAP + s] = j0 + 3; }
    }
    __syncthreads();
    if (t == 0) {
      int cc = *cp; if (cc > CAP) cc = CAP;
      cnt[i] = cc;
      float d = (float)(*cp) + 1.0f;    // + self loop
      deg[i] = d;
      rsd[i] = 1.0f / sqrtf(d);
    }
    return;
  }

  // ---- gemm path: 64x64 tile, 4x4 register tile per thread ----
  if (b == 0 && t < 2) bar[t] = 0u;           // barrier init (stream-ordered)
  const int rb = b & (N_NODES / BR - 1);      // 0..63
  const int ks = b >> 6;                      // 0..ksplit-1
  const int r0 = rb * BR;
  const int kbeg = (IN_DIM * ks) / ksplit;
  const int kend = (IN_DIM * (ks + 1)) / ksplit;
  const int rg = t >> 4;
  const int cg = t & 15;
  float* Xs = lds;                            // [KT][BR+4]
  float* Ws = lds + KT * (BR + 4);            // [KT][HID]

  float acc[4][4];
  #pragma unroll
  for (int r = 0; r < 4; ++r)
    #pragma unroll
    for (int c = 0; c < 4; ++c) acc[r][c] = 0.0f;

  for (int k0 = kbeg; k0 < kend; k0 += KT) {
    #pragma unroll
    for (int j = 0; j < (BR * KT) / 256; ++j) {   // 8 elems/thread
      int e = t + 256 * j;
      int row = e >> 5;
      int kk  = e & (KT - 1);
      int k   = k0 + kk;
      float v = (k < kend) ? X[(size_t)(r0 + row) * IN_DIM + k] : 0.0f;
      Xs[kk * (BR + 4) + row] = v;
    }
    #pragma unroll
    for (int j = 0; j < (HID * KT) / 256; ++j) {  // 8 elems/thread
      int e = t + 256 * j;
      int kk  = e >> 6;
      int col = e & 63;
      int k   = k0 + kk;
      Ws[kk * HID + col] = (k < kend) ? w1[(size_t)k * HID + col] : 0.0f;
    }
    __syncthreads();
    #pragma unroll
    for (int kk = 0; kk < KT; ++kk) {
      const float4 xv = *(const float4*)&Xs[kk * (BR + 4) + rg * 4];
      const float4 wv = *(const float4*)&Ws[kk * HID + cg * 4];
      float xr[4] = {xv.x, xv.y, xv.z, xv.w};
      float wc[4] = {wv.x, wv.y, wv.z, wv.w};
      #pragma unroll
      for (int r = 0; r < 4; ++r)
        #pragma unroll
        for (int c = 0; c < 4; ++c) acc[r][c] += xr[r] * wc[c];
    }
    __syncthreads();
  }
  float* Pp = P + (size_t)ks * N_NODES * HID;
  #pragma unroll
  for (int r = 0; r < 4; ++r) {
    int row = r0 + rg * 4 + r;
    float4 v = make_float4(acc[r][0], acc[r][1], acc[r][2], acc[r][3]);
    *(float4*)&Pp[(size_t)row * HID + cg * 4] = v;
  }
}

// ---------------------------------------------------------------------------
// Kernel 2 (fused reduce_h + mlp_out): one 64-lane wave per row. (R8, passed)
// ---------------------------------------------------------------------------
__global__ __launch_bounds__(256) void reduce_mlp(const float* __restrict__ P,
    const float* __restrict__ b1, const float* __restrict__ w2,
    const float* __restrict__ b2, float* __restrict__ F0,
    float* __restrict__ Fcur, int ksplit) {
  const int wave = threadIdx.x >> 6;
  const int lane = threadIdx.x & 63;
  const int row  = blockIdx.x * 4 + wave;            // grid 1024 x 4 waves

  float h = 0.0f;
  const float* p = P + (size_t)row * HID + lane;
  for (int ks = 0; ks < ksplit; ++ks)
    h += p[(size_t)ks * N_NODES * HID];
  float hv = fmaxf(h + b1[lane], 0.0f);

  float a0 = hv * w2[lane * OUT_DIM + 0];
  float a1 = hv * w2[lane * OUT_DIM + 1];
  float a2 = hv * w2[lane * OUT_DIM + 2];
  float a3 = hv * w2[lane * OUT_DIM + 3];
  float a4 = hv * w2[lane * OUT_DIM + 4];
  float a5 = hv * w2[lane * OUT_DIM + 5];
  float a6 = hv * w2[lane * OUT_DIM + 6];
  #pragma unroll
  for (int off = 32; off > 0; off >>= 1) {
    a0 += __shfl_xor(a0, off);
    a1 += __shfl_xor(a1, off);
    a2 += __shfl_xor(a2, off);
    a3 += __shfl_xor(a3, off);
    a4 += __shfl_xor(a4, off);
    a5 += __shfl_xor(a5, off);
    a6 += __shfl_xor(a6, off);
  }
  if (lane == 0) {
    float o[FPAD] = {a0 + b2[0], a1 + b2[1], a2 + b2[2], a3 + b2[3],
                     a4 + b2[4], a5 + b2[5], a6 + b2[6], 0.0f};
    float4 v0 = make_float4(o[0], o[1], o[2], o[3]);
    float4 v1 = make_float4(o[4], o[5], o[6], o[7]);
    float4* f0p = (float4*)(F0  + (size_t)row * FPAD);
    float4* fcp = (float4*)(Fcur + (size_t)row * FPAD);
    f0p[0] = v0; f0p[1] = v1;
    fcp[0] = v0; fcp[1] = v1;
  }
}

// ---------------------------------------------------------------------------
// Coherent (sc0 sc1: write-through / read-through the chip-coherent point)
// F access. All inter-step F traffic uses these -> NO threadfence (wbl2/inv)
// needed anywhere. waitcnt lives INSIDE the asm with its outputs (rule #18).
// Operands are ext_vector f32x4 (direct VGPR-quad; HIP float4 is a struct
// and is rejected as an asm "v" operand - R10 compile failure).
// ---------------------------------------------------------------------------
__device__ __forceinline__ void ld2_coh(const float* p, f32x4& a, f32x4& b) {
  asm volatile(
      "global_load_dwordx4 %0, %2, off sc0 sc1\n\t"
      "global_load_dwordx4 %1, %2, off offset:16 sc0 sc1\n\t"
      "s_waitcnt vmcnt(0)"
      : "=&v"(a), "=&v"(b) : "v"(p) : "memory");
}

__device__ __forceinline__ void st2_coh(float* p, f32x4 a, f32x4 b) {
  asm volatile(
      "global_store_dwordx4 %0, %1, off sc0 sc1\n\t"
      "global_store_dwordx4 %0, %2, off offset:16 sc0 sc1\n\t"
      "s_waitcnt vmcnt(0)"
      :: "v"(p), "v"(a), "v"(b) : "memory");
}

// 8 neighbor rows (2x f32x4 each): issue all 16 loads, ONE vmcnt(0) ->
// coherent-point latency paid once per step, not 8x.
__device__ __forceinline__ void ld8x2_coh(
    const float* p0, const float* p1, const float* p2, const float* p3,
    const float* p4, const float* p5, const float* p6, const float* p7,
    f32x4& a0, f32x4& b0, f32x4& a1, f32x4& b1,
    f32x4& a2, f32x4& b2, f32x4& a3, f32x4& b3,
    f32x4& a4, f32x4& b4, f32x4& a5, f32x4& b5,
    f32x4& a6, f32x4& b6, f32x4& a7, f32x4& b7) {
  asm volatile(
      "global_load_dwordx4 %0, %16, off sc0 sc1\n\t"
      "global_load_dwordx4 %1, %16, off offset:16 sc0 sc1\n\t"
      "global_load_dwordx4 %2, %17, off sc0 sc1\n\t"
      "global_load_dwordx4 %3, %17, off offset:16 sc0 sc1\n\t"
      "global_load_dwordx4 %4, %18, off sc0 sc1\n\t"
      "global_load_dwordx4 %5, %18, off offset:16 sc0 sc1\n\t"
      "global_load_dwordx4 %6, %19, off sc0 sc1\n\t"
      "global_load_dwordx4 %7, %19, off offset:16 sc0 sc1\n\t"
      "global_load_dwordx4 %8, %20, off sc0 sc1\n\t"
      "global_load_dwordx4 %9, %20, off offset:16 sc0 sc1\n\t"
      "global_load_dwordx4 %10, %21, off sc0 sc1\n\t"
      "global_load_dwordx4 %11, %21, off offset:16 sc0 sc1\n\t"
      "global_load_dwordx4 %12, %22, off sc0 sc1\n\t"
      "global_load_dwordx4 %13, %22, off offset:16 sc0 sc1\n\t"
      "global_load_dwordx4 %14, %23, off sc0 sc1\n\t"
      "global_load_dwordx4 %15, %23, off offset:16 sc0 sc1\n\t"
      "s_waitcnt vmcnt(0)"
      : "=&v"(a0), "=&v"(b0), "=&v"(a1), "=&v"(b1),
        "=&v"(a2), "=&v"(b2), "=&v"(a3), "=&v"(b3),
        "=&v"(a4), "=&v"(b4), "=&v"(a5), "=&v"(b5),
        "=&v"(a6), "=&v"(b6), "=&v"(a7), "=&v"(b7)
      : "v"(p0), "v"(p1), "v"(p2), "v"(p3),
        "v"(p4), "v"(p5), "v"(p6), "v"(p7)
      : "memory");
}

// ---------------------------------------------------------------------------
// Fence-free inter-workgroup barrier.
//  - arrival: relaxed fetch_add (serviced at coherent point).
//  - poll: relaxed load, with an RMW fetch_add(0) every 16th iteration
//    (RMW always goes to the coherent point -> cannot spin on a stale line
//    forever; the piece R4 lacked and R6 proved).
//  - iteration timeout: worst case = failed test, never a hung container.
//  - NO threadfence: data visibility is carried by the sc0/sc1 F path
//    (store ack'd at coherent point BEFORE arrival RMW is issued).
// ---------------------------------------------------------------------------
__device__ __forceinline__ void grid_barrier(unsigned* __restrict__ bar,
                                             unsigned step1) {
  __syncthreads();   // all groups' st2_coh already ack'd (vmcnt(0) in-asm)
  if (threadIdx.x == 0) {
    __hip_atomic_fetch_add(&bar[0], 1u, __ATOMIC_RELAXED,
                           __HIP_MEMORY_SCOPE_AGENT);
    const unsigned want = (unsigned)NBLK * step1;
    unsigned it = 0;
    for (;;) {
      unsigned v;
      if ((it & 15u) == 15u)
        v = __hip_atomic_fetch_add(&bar[0], 0u, __ATOMIC_RELAXED,
                                   __HIP_MEMORY_SCOPE_AGENT);
      else
        v = __hip_atomic_load(&bar[0], __ATOMIC_RELAXED,
                              __HIP_MEMORY_SCOPE_AGENT);
      if (v >= want) break;
      if (++it > (1u << 22)) break;      // failsafe: fail test, not GPU
      __builtin_amdgcn_s_sleep(4);
    }
  }
  __syncthreads();
}

// ---------------------------------------------------------------------------
// Kernel 3 (fused): ALL 10 RUNG steps, one launch. Body identical to R6's
// passing kernel; data path = sc0/sc1 coherent ops; barrier = fence-free.
// 64 blocks x 256 threads = 4 lanes/node; first 8 edges/lane cached in
// named registers (covers ci<=32); tail loop for ci>32.
// ---------------------------------------------------------------------------
__global__ __launch_bounds__(256) void rung_fused(const float* __restrict__ F0,
    float* __restrict__ FA, float* __restrict__ FB, float* __restrict__ out,
    const int* __restrict__ nbr, const int* __restrict__ cnt,
    const float* __restrict__ deg, const float* __restrict__ rsd,
    const float* __restrict__ lg0p, const float* __restrict__ rdp,
    unsigned* __restrict__ bar) {
  const int lane = threadIdx.x & 3;
  const int i = (blockIdx.x * 256 + threadIdx.x) >> 2;     // node id 0..4095

  const float r_ = 1.0f / (1.0f + expf(-rdp[0]));
  const float g0 = expf(lg0p[0]);
  const float rsi = rsd[i];
  const float Di  = deg[i];
  const int   ci  = cnt[i];

  const int* nb = nbr + (size_t)i * CAP;
  int   j0=0,j1=0,j2=0,j3=0,j4=0,j5=0,j6=0,j7=0;
  float q0=0,q1=0,q2=0,q3=0,q4=0,q5=0,q6=0,q7=0;
  bool  e0=(lane    <ci), e1=(lane+ 4<ci), e2=(lane+ 8<ci), e3=(lane+12<ci),
        e4=(lane+16<ci), e5=(lane+20<ci), e6=(lane+24<ci), e7=(lane+28<ci);
  if (e0) { j0 = nb[lane     ]; q0 = rsd[j0]; }
  if (e1) { j1 = nb[lane +  4]; q1 = rsd[j1]; }
  if (e2) { j2 = nb[lane +  8]; q2 = rsd[j2]; }
  if (e3) { j3 = nb[lane + 12]; q3 = rsd[j3]; }
  if (e4) { j4 = nb[lane + 16]; q4 = rsd[j4]; }
  if (e5) { j5 = nb[lane + 20]; q5 = rsd[j5]; }
  if (e6) { j6 = nb[lane + 24]; q6 = rsd[j6]; }
  if (e7) { j7 = nb[lane + 28]; q7 = rsd[j7]; }

  const float* cur = FA;
  float*       nxt = FB;
  float rk = 1.0f;

  for (int k = 0; k < 10; ++k) {
    const float lam = g0 * rk * (1.0f / SCADA);
    rk *= r_;

    // own row (changed last step -> coherent read)
    f32x4 a0r, a1r;
    ld2_coh(cur + (size_t)i * FPAD, a0r, a1r);
    float Fni[FPAD] = {a0r.x * rsi, a0r.y * rsi, a0r.z * rsi, a0r.w * rsi,
                       a1r.x * rsi, a1r.y * rsi, a1r.z * rsi, a1r.w * rsi};

    // all 8 cached-edge rows in one shot (absent edges read row 0: harmless)
    f32x4 A0,B0,A1,B1,A2,B2,A3,B3,A4,B4,A5,B5,A6,B6,A7,B7;
    ld8x2_coh(cur + (size_t)j0 * FPAD, cur + (size_t)j1 * FPAD,
              cur + (size_t)j2 * FPAD, cur + (size_t)j3 * FPAD,
              cur + (size_t)j4 * FPAD, cur + (size_t)j5 * FPAD,
              cur + (size_t)j6 * FPAD, cur + (size_t)j7 * FPAD,
              A0,B0,A1,B1,A2,B2,A3,B3,A4,B4,A5,B5,A6,B6,A7,B7);

    float s = 0.0f;
    float acc[FPAD] = {0, 0, 0, 0, 0, 0, 0, 0};

    #define EDGEV(EN, QN, VA, VB)                                             \
    if (EN) {                                                                 \
      float fj[FPAD] = {VA.x, VA.y, VA.z, VA.w, VB.x, VB.y, VB.z, VB.w};      \
      float d2 = 0.0f;                                                        \
      _Pragma("unroll")                                                       \
      for (int c = 0; c < FPAD; ++c) {                                        \
        float df = Fni[c] - fj[c] * (QN);                                     \
        d2 += df * df;                                                        \
      }                                                                       \
      float y = sqrtf(d2);                                                    \
      float w;                                                                \
      if (y <= lam)              w = 1.0f;                                    \
      else if (y <= SCADA * lam) w = (SCADA * lam - y) /                      \
                                     ((SCADA - 1.0f) * fmaxf(y, 1e-12f));     \
      else                       w = 0.0f;                                    \
      if (w != w) w = 1.0f;                                                   \
      s += w;                                                                 \
      float wr = w * rsi * (QN);                                              \
      _Pragma("unroll")                                                       \
      for (int c = 0; c < FPAD; ++c) acc[c] += wr * fj[c];                    \
    }
    EDGEV(e0, q0, A0, B0) EDGEV(e1, q1, A1, B1)
    EDGEV(e2, q2, A2, B2) EDGEV(e3, q3, A3, B3)
    EDGEV(e4, q4, A4, B4) EDGEV(e5, q5, A5, B5)
    EDGEV(e6, q6, A6, B6) EDGEV(e7, q7, A7, B7)

    // tail: edges with index >= 32 (ci > 32)
    for (int l = lane + 32; l < ci; l += 4) {
      int jt = nb[l];
      float qt = rsd[jt];
      f32x4 ta, tb;
      ld2_coh(cur + (size_t)jt * FPAD, ta, tb);
      EDGEV(true, qt, ta, tb)
    }
    #undef EDGEV

    // reduce across the 4-lane node group
    #pragma unroll
    for (int off = 2; off > 0; off >>= 1) {
      s += __shfl_xor(s, off, 4);
      #pragma unroll
      for (int c = 0; c < FPAD; ++c) acc[c] += __shfl_xor(acc[c], off, 4);
    }

    if (k == 9) {
      if (lane == 0) {
        float inv = 1.0f / (s / Di + LAMBDA);
        #pragma unroll
        for (int c = 0; c < OUT_DIM; ++c)
          out[(size_t)i * OUT_DIM + c] =
              (acc[c] + LAMBDA * F0[(size_t)i * FPAD + c]) * inv;
        // normal stores: kernel-end flush makes them host-visible
      }
    } else {
      if (lane == 0) {
        float inv = 1.0f / (s / Di + LAMBDA);
        float o[FPAD];
        #pragma unroll
        for (int c = 0; c < FPAD; ++c)
          o[c] = (acc[c] + LAMBDA * F0[(size_t)i * FPAD + c]) * inv;  // pad stays 0
        f32x4 v0 = {o[0], o[1], o[2], o[3]};
        f32x4 v1 = {o[4], o[5], o[6], o[7]};
        st2_coh(nxt + (size_t)i * FPAD, v0, v1);
      }
      grid_barrier(bar, (unsigned)(k + 1));
      const float* tmp = cur; cur = nxt; nxt = (float*)tmp;
    }
  }
}

// ---------------------------------------------------------------------------
extern "C" void kernel_launch(void* const* d_in, const int* in_sizes, int n_in,
                              void* d_out, int out_size, void* d_ws, size_t ws_size,
                              hipStream_t stream) {
  const float* A   = (const float*)d_in[0];
  const float* X   = (const float*)d_in[1];
  const float* w1  = (const float*)d_in[2];
  const float* b1  = (const float*)d_in[3];
  const float* w2  = (const float*)d_in[4];
  const float* b2  = (const float*)d_in[5];
  const float* lg0 = (const float*)d_in[6];
  const float* rd  = (const float*)d_in[7];
  float* out = (float*)d_out;

  const size_t fixed = (size_t)N_NODES * CAP * sizeof(int)        // nbr
                     + (size_t)N_NODES * sizeof(int)              // cnt
                     + (size_t)N_NODES * sizeof(float) * 2        // deg, rsd
                     + (size_t)N_NODES * FPAD * sizeof(float) * 3 // F0, FA, FB
                     + 256;                                       // barrier
  const size_t pbuf = (size_t)N_NODES * HID * sizeof(float);
  int ksplit = (ws_size >= fixed + 16 * pbuf) ? 16 : 8;

  char* w = (char*)d_ws;
  int*   nbr = (int*)w;   w += (size_t)N_NODES * CAP * sizeof(int);
  int*   cnt = (int*)w;   w += (size_t)N_NODES * sizeof(int);
  float* deg = (float*)w; w += (size_t)N_NODES * sizeof(float);
  float* rsd = (float*)w; w += (size_t)N_NODES * sizeof(float);
  float* P   = (float*)w; w += (size_t)ksplit * N_NODES * HID * sizeof(float);
  float* F0  = (float*)w; w += (size_t)N_NODES * FPAD * sizeof(float);
  float* FA  = (float*)w; w += (size_t)N_NODES * FPAD * sizeof(float);
  float* FB  = (float*)w; w += (size_t)N_NODES * FPAD * sizeof(float);
  unsigned* bar = (unsigned*)w;  // monotonic arrival counter

  front<<<(N_NODES / BR) * ksplit + N_NODES, 256, 0, stream>>>(
      A, X, w1, nbr, cnt, deg, rsd, P, bar, ksplit);
  reduce_mlp<<<N_NODES / 4, 256, 0, stream>>>(P, b1, w2, b2, F0, FA, ksplit);
  rung_fused<<<NBLK, 256, 0, stream>>>(F0, FA, FB, out, nbr, cnt, deg, rsd,
                                       lg0, rd, bar);
}

// Round 12
// 200.510 us; speedup vs baseline: 1.4655x; 1.4655x over previous
//
#include <hip/hip_runtime.h>
#include <math.h>

#define N_NODES 4096
#define IN_DIM  1433
#define HID     64
#define OUT_DIM 7
#define FPAD    8       // padded feature stride for vectorized gathers
#define CAP     128     // max neighbors per node (avg 32, sigma 5.6; 128 >15 sigma)
#define BR      64      // rows per gemm tile block
#define KT      32      // k-tile
#define LPN     16      // lanes per node in rung_step (avg degree 32 -> 2 edges/lane)

static constexpr float LAMBDA = (float)(1.0 / 0.9 - 1.0);   // 0.11111111
static constexpr float SCADA  = 3.7f;

// ---------------------------------------------------------------------------
// Kernel 1 (heterogeneous fused front), gemm-first block order (R8, 204.7us):
//   blocks [0, NGEMM)            : gemm1 split-K tiles, P[ks] = X_chunk @ w1
//   blocks [NGEMM, NGEMM+N_NODES): adjacency extraction, one row per block
// First adj block also writes the lam_k table.
// Session verdict on this kernel: latency-bound (hbm 17%, VALU 23%), floor
// ~46us; dispatch reorder / ksplit / fusion-overlap all neutral.
// ---------------------------------------------------------------------------
__global__ __launch_bounds__(256) void front(const float* __restrict__ A,
    const float* __restrict__ X, const float* __restrict__ w1,
    int* __restrict__ nbr, int* __restrict__ cnt, float* __restrict__ deg,
    float* __restrict__ rsd, float* __restrict__ P, float* __restrict__ lamt,
    const float* __restrict__ lg0p, const float* __restrict__ rdp, int ksplit) {
  __shared__ __align__(16) float lds[KT * (BR + 4) + KT * HID];
  const int b = blockIdx.x;
  const int t = threadIdx.x;
  const int ngemm = (N_NODES / BR) * ksplit;

  if (b >= ngemm) {
    // ---- adjacency path (one row per block) ----
    const int i = b - ngemm;
    if (i == 0 && t == 0) {
      float r_ = 1.0f / (1.0f + expf(-rdp[0]));
      float g  = expf(lg0p[0]) * (1.0f / SCADA);
      #pragma unroll
      for (int k = 0; k < 10; ++k) { lamt[k] = g; g *= r_; }
    }
    int* cp = (int*)lds;
    if (t == 0) *cp = 0;
    __syncthreads();
    const float4* row = (const float4*)(A + (size_t)i * N_NODES);
    #pragma unroll
    for (int q = t; q < N_NODES / 4; q += 256) {
      float4 v = row[q];
      int j0 = q * 4;
      if (v.x != 0.0f) { int s = atomicAdd(cp, 1); if (s < CAP) nbr[(size_t)i * CAP + s] = j0; }
      if (v.y != 0.0f) { int s = atomicAdd(cp, 1); if (s < CAP) nbr[(size_t)i * CAP + s] = j0 + 1; }
      if (v.z != 0.0f) { int s = atomicAdd(cp, 1); if (s < CAP) nbr[(size_t)i * CAP + s] = j0 + 2; }
      if (v.w != 0.0f) { int s = atomicAdd(cp, 1); if (s < CAP) nbr[(size_t)i * CAP + s] = j0 + 3; }
    }
    __syncthreads();
    if (t == 0) {
      int cc = *cp; if (cc > CAP) cc = CAP;
      cnt[i] = cc;
      float d = (float)(*cp) + 1.0f;    // + self loop
      deg[i] = d;
      rsd[i] = 1.0f / sqrtf(d);
    }
    return;
  }

  // ---- gemm path: 64x64 tile, 4x4 register tile per thread ----
  const int rb = b & (N_NODES / BR - 1);      // 0..63
  const int ks = b >> 6;                      // 0..ksplit-1
  const int r0 = rb * BR;
  const int kbeg = (IN_DIM * ks) / ksplit;
  const int kend = (IN_DIM * (ks + 1)) / ksplit;
  const int rg = t >> 4;
  const int cg = t & 15;
  float* Xs = lds;                            // [KT][BR+4]
  float* Ws = lds + KT * (BR + 4);            // [KT][HID]

  float acc[4][4];
  #pragma unroll
  for (int r = 0; r < 4; ++r)
    #pragma unroll
    for (int c = 0; c < 4; ++c) acc[r][c] = 0.0f;

  for (int k0 = kbeg; k0 < kend; k0 += KT) {
    #pragma unroll
    for (int j = 0; j < (BR * KT) / 256; ++j) {   // 8 scalar X elems/thread
      int e = t + 256 * j;
      int row = e >> 5;
      int kk  = e & (KT - 1);
      int k   = k0 + kk;
      float v = (k < kend) ? X[(size_t)(r0 + row) * IN_DIM + k] : 0.0f;
      Xs[kk * (BR + 4) + row] = v;
    }
    #pragma unroll
    for (int j = 0; j < (HID * KT) / (256 * 4); ++j) {  // 2 float4 w1/thread (R9, passed)
      int f = t + 256 * j;                // 512 float4 slots
      int kk   = f >> 4;                  // 16 float4 per kk-row
      int colq = f & 15;
      int k    = k0 + kk;
      float4 v = make_float4(0.f, 0.f, 0.f, 0.f);
      if (k < kend) v = *(const float4*)&w1[(size_t)k * HID + colq * 4];
      *(float4*)&Ws[kk * HID + colq * 4] = v;
    }
    __syncthreads();
    #pragma unroll
    for (int kk = 0; kk < KT; ++kk) {
      const float4 xv = *(const float4*)&Xs[kk * (BR + 4) + rg * 4];
      const float4 wv = *(const float4*)&Ws[kk * HID + cg * 4];
      float xr[4] = {xv.x, xv.y, xv.z, xv.w};
      float wc[4] = {wv.x, wv.y, wv.z, wv.w};
      #pragma unroll
      for (int r = 0; r < 4; ++r)
        #pragma unroll
        for (int c = 0; c < 4; ++c) acc[r][c] += xr[r] * wc[c];
    }
    __syncthreads();
  }
  float* Pp = P + (size_t)ks * N_NODES * HID;
  #pragma unroll
  for (int r = 0; r < 4; ++r) {
    int row = r0 + rg * 4 + r;
    float4 v = make_float4(acc[r][0], acc[r][1], acc[r][2], acc[r][3]);
    *(float4*)&Pp[(size_t)row * HID + cg * 4] = v;
  }
}

// ---------------------------------------------------------------------------
// Kernel 2 (fused reduce_h + mlp_out): one 64-lane wave per row. (R8, passed)
// ---------------------------------------------------------------------------
__global__ __launch_bounds__(256) void reduce_mlp(const float* __restrict__ P,
    const float* __restrict__ b1, const float* __restrict__ w2,
    const float* __restrict__ b2, float* __restrict__ F0,
    float* __restrict__ Fcur, int ksplit) {
  const int wave = threadIdx.x >> 6;
  const int lane = threadIdx.x & 63;
  const int row  = blockIdx.x * 4 + wave;            // grid 1024 x 4 waves

  float h = 0.0f;
  const float* p = P + (size_t)row * HID + lane;
  for (int ks = 0; ks < ksplit; ++ks)
    h += p[(size_t)ks * N_NODES * HID];
  float hv = fmaxf(h + b1[lane], 0.0f);

  float a0 = hv * w2[lane * OUT_DIM + 0];
  float a1 = hv * w2[lane * OUT_DIM + 1];
  float a2 = hv * w2[lane * OUT_DIM + 2];
  float a3 = hv * w2[lane * OUT_DIM + 3];
  float a4 = hv * w2[lane * OUT_DIM + 4];
  float a5 = hv * w2[lane * OUT_DIM + 5];
  float a6 = hv * w2[lane * OUT_DIM + 6];
  #pragma unroll
  for (int off = 32; off > 0; off >>= 1) {
    a0 += __shfl_xor(a0, off);
    a1 += __shfl_xor(a1, off);
    a2 += __shfl_xor(a2, off);
    a3 += __shfl_xor(a3, off);
    a4 += __shfl_xor(a4, off);
    a5 += __shfl_xor(a5, off);
    a6 += __shfl_xor(a6, off);
  }
  if (lane == 0) {
    float o[FPAD] = {a0 + b2[0], a1 + b2[1], a2 + b2[2], a3 + b2[3],
                     a4 + b2[4], a5 + b2[5], a6 + b2[6], 0.0f};
    float4 v0 = make_float4(o[0], o[1], o[2], o[3]);
    float4 v1 = make_float4(o[4], o[5], o[6], o[7]);
    float4* f0p = (float4*)(F0  + (size_t)row * FPAD);
    float4* fcp = (float4*)(Fcur + (size_t)row * FPAD);
    f0p[0] = v0; f0p[1] = v1;
    fcp[0] = v0; fcp[1] = v1;
  }
}

// ---------------------------------------------------------------------------
// Kernel 3: one RUNG propagation step. 16 lanes per node, 4-level reduce.
// 10 sequential launches: proven CHEAPER than any single-kernel fusion on
// this chip (cross-XCD barrier floor ~13.5us/sync fence-free vs ~6us/launch;
// measured across CG=473us, fenced=180us, fence-free=149us vs train=~60us).
// ---------------------------------------------------------------------------
__global__ __launch_bounds__(256) void rung_step(const float* __restrict__ Fin,
    const float* __restrict__ F0, float* __restrict__ Fout,
    const int* __restrict__ nbr, const int* __restrict__ cnt,
    const float* __restrict__ deg, const float* __restrict__ rsd,
    const float* __restrict__ lamt, int kstep, int last) {
  const int lane = threadIdx.x & (LPN - 1);
  const int i = (blockIdx.x * 256 + threadIdx.x) / LPN;    // node id 0..4095

  const float lam = lamt[kstep];
  const float rsi = rsd[i];
  const float Di  = deg[i];
  const int   ci  = cnt[i];

  float Fni[FPAD];
  {
    const float4* fp = (const float4*)(Fin + (size_t)i * FPAD);
    float4 a0 = fp[0], a1 = fp[1];
    Fni[0] = a0.x * rsi; Fni[1] = a0.y * rsi; Fni[2] = a0.z * rsi; Fni[3] = a0.w * rsi;
    Fni[4] = a1.x * rsi; Fni[5] = a1.y * rsi; Fni[6] = a1.z * rsi; Fni[7] = a1.w * rsi;
  }
  float s = 0.0f;
  float acc[FPAD] = {0, 0, 0, 0, 0, 0, 0, 0};
  const int* nb = nbr + (size_t)i * CAP;
  for (int l = lane; l < ci; l += LPN) {
    int j = nb[l];
    float rsj = rsd[j];
    const float4* fp = (const float4*)(Fin + (size_t)j * FPAD);
    float4 b0 = fp[0], b1v = fp[1];
    float fj[FPAD] = {b0.x, b0.y, b0.z, b0.w, b1v.x, b1v.y, b1v.z, b1v.w};
    float d2 = 0.0f;
    #pragma unroll
    for (int c = 0; c < FPAD; ++c) {
      float df = Fni[c] - fj[c] * rsj;
      d2 += df * df;
    }
    float y = sqrtf(d2);
    float w;
    if (y <= lam)              w = 1.0f;
    else if (y <= SCADA * lam) w = (SCADA * lam - y) / ((SCADA - 1.0f) * fmaxf(y, 1e-12f));
    else                       w = 0.0f;
    if (w != w) w = 1.0f;      // NaN guard (matches reference)
    s += w;
    float wr = w * rsi * rsj;  // W_ij * A_tilde_ij
    #pragma unroll
    for (int c = 0; c < FPAD; ++c) acc[c] += wr * fj[c];
  }
  #pragma unroll
  for (int off = LPN / 2; off > 0; off >>= 1) {
    s += __shfl_xor(s, off, LPN);
    #pragma unroll
    for (int c = 0; c < FPAD; ++c) acc[c] += __shfl_xor(acc[c], off, LPN);
  }
  if (lane == 0) {
    float Q = s / Di + LAMBDA;
    float inv = 1.0f / Q;
    if (last) {
      #pragma unroll
      for (int c = 0; c < OUT_DIM; ++c)
        Fout[(size_t)i * OUT_DIM + c] = (acc[c] + LAMBDA * F0[(size_t)i * FPAD + c]) * inv;
    } else {
      float o[FPAD];
      #pragma unroll
      for (int c = 0; c < FPAD; ++c)
        o[c] = (acc[c] + LAMBDA * F0[(size_t)i * FPAD + c]) * inv;   // pad col stays 0
      float4* op = (float4*)(Fout + (size_t)i * FPAD);
      op[0] = make_float4(o[0], o[1], o[2], o[3]);
      op[1] = make_float4(o[4], o[5], o[6], o[7]);
    }
  }
}

// ---------------------------------------------------------------------------
extern "C" void kernel_launch(void* const* d_in, const int* in_sizes, int n_in,
                              void* d_out, int out_size, void* d_ws, size_t ws_size,
                              hipStream_t stream) {
  const float* A   = (const float*)d_in[0];
  const float* X   = (const float*)d_in[1];
  const float* w1  = (const float*)d_in[2];
  const float* b1  = (const float*)d_in[3];
  const float* w2  = (const float*)d_in[4];
  const float* b2  = (const float*)d_in[5];
  const float* lg0 = (const float*)d_in[6];
  const float* rd  = (const float*)d_in[7];
  float* out = (float*)d_out;

  const size_t fixed = (size_t)N_NODES * CAP * sizeof(int)        // nbr
                     + (size_t)N_NODES * sizeof(int)              // cnt
                     + (size_t)N_NODES * sizeof(float) * 2        // deg, rsd
                     + (size_t)N_NODES * FPAD * sizeof(float) * 3 // F0, FA, FB
                     + 64;                                        // lam table
  const size_t pbuf = (size_t)N_NODES * HID * sizeof(float);
  int ksplit = (ws_size >= fixed + 16 * pbuf) ? 16 : 8;

  char* w = (char*)d_ws;
  int*   nbr = (int*)w;   w += (size_t)N_NODES * CAP * sizeof(int);
  int*   cnt = (int*)w;   w += (size_t)N_NODES * sizeof(int);
  float* deg = (float*)w; w += (size_t)N_NODES * sizeof(float);
  float* rsd = (float*)w; w += (size_t)N_NODES * sizeof(float);
  float* P   = (float*)w; w += (size_t)ksplit * N_NODES * HID * sizeof(float);
  float* F0  = (float*)w; w += (size_t)N_NODES * FPAD * sizeof(float);
  float* FA  = (float*)w; w += (size_t)N_NODES * FPAD * sizeof(float);
  float* FB  = (float*)w; w += (size_t)N_NODES * FPAD * sizeof(float);
  float* lamt = (float*)w;

  // fused front, gemm tiles first (R8 structure, best measured: 204.7us)
  front<<<(N_NODES / BR) * ksplit + N_NODES, 256, 0, stream>>>(
      A, X, w1, nbr, cnt, deg, rsd, P, lamt, lg0, rd, ksplit);
  reduce_mlp<<<N_NODES / 4, 256, 0, stream>>>(P, b1, w2, b2, F0, FA, ksplit);

  float* cur = FA;
  float* nxt = FB;
  for (int k = 0; k < 10; ++k) {
    int last = (k == 9);
    float* dst = last ? out : nxt;
    rung_step<<<(N_NODES * LPN) / 256, 256, 0, stream>>>(cur, F0, dst, nbr, cnt,
                                                         deg, rsd, lamt, k, last);
    float* tmp = cur; cur = nxt; nxt = tmp;
  }
}